// Round 3
// baseline (894.439 us; speedup 1.0000x reference)
//
#include <hip/hip_runtime.h>

// ---------------- problem constants ----------------
#define C_CH   512
#define HFEAT  50
#define WFEAT  50
#define NROIS  256
#define D1     25088   // C_CH * 49
#define H1     4096
#define NHEAD  105     // 21 + 84

typedef __attribute__((ext_vector_type(8))) short short8;
typedef __attribute__((ext_vector_type(4))) float f32x4;

__device__ __forceinline__ unsigned short f2bf(float f) {
  unsigned int u = __float_as_uint(f);
  unsigned int r = (u + 0x7fffu + ((u >> 16) & 1u)) >> 16;
  return (unsigned short)r;
}

// ---------------- feature transpose: [C,H,W] -> [H*W, C] ----------------
__global__ __launch_bounds__(512)
void transpose_feat(const float* __restrict__ feat, float* __restrict__ featT) {
  const int yx = blockIdx.x;        // 0 .. 2499
  const int c  = threadIdx.x;       // 0 .. 511
  featT[(size_t)yx * C_CH + c] = feat[(size_t)c * (HFEAT * WFEAT) + yx];
}

// ---------------- ROI max-pool (adaptive 7x7), fp32 -> bf16 ----------------
__global__ __launch_bounds__(512)
void roi_pool_kernel(const float* __restrict__ featT, const float* __restrict__ boxes,
                     unsigned short* __restrict__ pooled) {
  const int roi = blockIdx.x;
  const int bx1 = (int)(boxes[roi * 4 + 0] * 0.0625f);
  const int by1 = (int)(boxes[roi * 4 + 1] * 0.0625f);
  const int bx2 = (int)(boxes[roi * 4 + 2] * 0.0625f);
  const int by2 = (int)(boxes[roi * 4 + 3] * 0.0625f);

  const int rlo = min(max(by1, 0), HFEAT - 1);
  const int rhi = min(by2, HFEAT - 1);
  const int rn  = max(rhi - rlo + 1, 1);
  const int clo = min(max(bx1, 0), WFEAT - 1);
  const int chi = min(bx2, WFEAT - 1);
  const int cn  = max(chi - clo + 1, 1);

  const int c = threadIdx.x;                      // one channel per thread
  unsigned short* op = pooled + (size_t)roi * D1 + c * 49;

  for (int i = 0; i < 7; ++i) {
    const int r0 = rlo + (i * rn) / 7;
    const int r1 = rlo + ((i + 1) * rn + 6) / 7;
    for (int j = 0; j < 7; ++j) {
      const int c0 = clo + (j * cn) / 7;
      const int c1 = clo + ((j + 1) * cn + 6) / 7;
      float m = -3.402823466e+38f;
      for (int y = r0; y < r1; ++y)
        for (int x = c0; x < c1; ++x)
          m = fmaxf(m, featT[(size_t)(y * WFEAT + x) * C_CH + c]);
      op[i * 7 + j] = f2bf(m);
    }
  }
}

// ---------------- split-K MFMA GEMM: A[256,K] bf16  x  B[N,K] fp32 -> partials fp32 ----------------
// BM=256 (whole M), BN=32, BK=32, 256 threads = 4 waves (2m x 2n of 128x16).
// 4 blocks/CU (36KB LDS, <=128 VGPR) + 1-deep double-buffered pipeline:
// next tile's A global_load_lds + B register load issued BEFORE current MFMAs,
// B convert/ds_write after -> the barrier's vmcnt(0) waits on loads that had a
// full compute phase to land, and 4 blocks keep ~16KB/CU of HBM reads in flight
// (>= the ~9.6KB needed to sustain this kernel's 25.6 GB/s/CU HBM share).
// Each (z,bn) block owns a unique 32-row B slice -> B read from HBM exactly once.
// A's z-slice stays L2-resident per XCD via z = bid % NZ (z -> XCD round-robin).
template <int NZ, bool TWO_B>
__global__ __launch_bounds__(256, 4)
void gemm_bt_splitk(const unsigned short* __restrict__ A,  // [256,K] bf16 bits
                    const float* __restrict__ B,           // [*,K] fp32
                    const float* __restrict__ B2,          // [*,K] fp32 (heads only)
                    float* __restrict__ part,              // [NZ, 256, Nt]
                    const int Nt, const int K,
                    const int kps, const int n_valid) {
  __shared__ __align__(16) unsigned short As[2][256 * 32];  // 2 x 16 KB
  __shared__ __align__(16) unsigned short Bs[2][32 * 32];   // 2 x  2 KB

  const int bid = (int)blockIdx.x;
  const int z   = bid % NZ;                 // -> XCD pin per dispatch heuristic
  const int bn  = (bid / NZ) * 32;
  const int k0  = z * kps;
  const int nIter = kps >> 5;

  const int tid  = threadIdx.x;
  const int wave = tid >> 6;
  const int lane = tid & 63;
  const int lr   = lane & 15;   // fragment row (m or n)
  const int kq   = lane >> 4;   // k-quad: k = kq*8 .. +7
  const int wm   = (wave & 1) * 128;
  const int wn   = (wave >> 1) * 16;

  // B staging: 8 threads per row, 4 floats each
  const int  brow   = tid >> 3;          // 0..31
  const int  bseg   = (tid & 7) * 4;
  const int  nrow   = bn + brow;
  const bool bvalid = nrow < n_valid;
  const float* bsrc;
  if (TWO_B) {
    if (nrow < 21)       bsrc = B  + (size_t)nrow * K + bseg;
    else if (bvalid)     bsrc = B2 + (size_t)(nrow - 21) * K + bseg;
    else                 bsrc = B  + bseg;   // never dereferenced
  } else {
    bsrc = B + (size_t)nrow * K + bseg;
  }

  f32x4 acc[8];
#pragma unroll
  for (int im = 0; im < 8; ++im)
    acc[im] = (f32x4){0.f, 0.f, 0.f, 0.f};

  auto stageA = [&](int kk, int buf) {
#pragma unroll
    for (int i = 0; i < 4; ++i) {
      const int chunk = wave * 4 + i;            // 0..15, wave-uniform
      const int row   = chunk * 16 + (lane >> 2);
      const unsigned short* g = A + (size_t)row * K + kk + (lane & 3) * 8;
      __builtin_amdgcn_global_load_lds(
          (const __attribute__((address_space(1))) void*)g,
          (__attribute__((address_space(3))) void*)(&As[buf][chunk * 512]),
          16, 0, 0);
    }
  };
  auto loadB = [&](int kk) -> float4 {
    if (bvalid) return *(const float4*)(bsrc + kk);
    return make_float4(0.f, 0.f, 0.f, 0.f);
  };
  auto writeB = [&](float4 v, int buf) {
    union { unsigned short h[4]; unsigned long long u; } t;
    t.h[0] = f2bf(v.x); t.h[1] = f2bf(v.y); t.h[2] = f2bf(v.z); t.h[3] = f2bf(v.w);
    *(unsigned long long*)(&Bs[buf][brow * 32 + bseg]) = t.u;
  };

  // ---- prologue: stage tile 0 into buffer 0 ----
  stageA(k0, 0);
  writeB(loadB(k0), 0);
  __syncthreads();

  int cur = 0;
  for (int it = 0; it < nIter; ++it) {
    const int kk = k0 + (it << 5);
    const bool more = (it + 1) < nIter;
    float4 bnx;
    if (more) {                       // issue next tile's loads FIRST
      stageA(kk + 32, cur ^ 1);
      bnx = loadB(kk + 32);
    }
    // ---- compute current tile: 9 ds_read_b128 + 8 MFMA per wave ----
    short8 af[8], bf;
#pragma unroll
    for (int im = 0; im < 8; ++im)
      af[im] = *(const short8*)(&As[cur][(wm + im * 16 + lr) * 32 + kq * 8]);
    bf = *(const short8*)(&Bs[cur][(wn + lr) * 32 + kq * 8]);
#pragma unroll
    for (int im = 0; im < 8; ++im)
      acc[im] = __builtin_amdgcn_mfma_f32_16x16x32_bf16(af[im], bf, acc[im], 0, 0, 0);
    if (more) writeB(bnx, cur ^ 1);   // convert + LDS-write late
    __syncthreads();
    cur ^= 1;
  }

  // ---- write fp32 partials: C/D layout col=lane&15 (n), row=kq*4+r (m) ----
#pragma unroll
  for (int im = 0; im < 8; ++im) {
    const int m0 = wm + im * 16 + kq * 4;
    const int n  = bn + wn + lr;
    float* p = part + ((size_t)z * NROIS + m0) * Nt + n;
#pragma unroll
    for (int r = 0; r < 4; ++r)
      p[(size_t)r * Nt] = acc[im][r];
  }
}

// ---------------- split-K reduce + bias + relu + cast to bf16 ----------------
__global__ __launch_bounds__(256)
void reduce_bias_relu(const float* __restrict__ part, const float* __restrict__ bias,
                      unsigned short* __restrict__ out, const int MN, const int nmask,
                      const int S) {
  const int idx = (blockIdx.x * 256 + threadIdx.x) * 4;
  if (idx >= MN) return;
  float4 v = *(const float4*)(part + idx);
  for (int s = 1; s < S; ++s) {
    const float4 p = *(const float4*)(part + (size_t)s * MN + idx);
    v.x += p.x; v.y += p.y; v.z += p.z; v.w += p.w;
  }
  const float4 b = *(const float4*)(bias + (idx & nmask));
  v.x = fmaxf(v.x + b.x, 0.f);
  v.y = fmaxf(v.y + b.y, 0.f);
  v.z = fmaxf(v.z + b.z, 0.f);
  v.w = fmaxf(v.w + b.w, 0.f);
  unsigned long long o = (unsigned long long)f2bf(v.x)
                       | ((unsigned long long)f2bf(v.y) << 16)
                       | ((unsigned long long)f2bf(v.z) << 32)
                       | ((unsigned long long)f2bf(v.w) << 48);
  *(unsigned long long*)(out + idx) = o;
}

// ---------------- heads: reduce + bias, split into class/regr outputs ----------------
__global__ __launch_bounds__(128)
void heads_reduce(const float* __restrict__ part, const float* __restrict__ bc,
                  const float* __restrict__ br, float* __restrict__ out, const int S) {
  const int m = blockIdx.x;
  const int n = threadIdx.x;
  if (n >= NHEAD) return;
  float v = 0.f;
  for (int s = 0; s < S; ++s) v += part[((size_t)s * NROIS + m) * 128 + n];
  if (n < 21) out[m * 21 + n] = v + bc[n];
  else        out[NROIS * 21 + m * 84 + (n - 21)] = v + br[n - 21];
}

// ---------------- launch ----------------
extern "C" void kernel_launch(void* const* d_in, const int* in_sizes, int n_in,
                              void* d_out, int out_size, void* d_ws, size_t ws_size,
                              hipStream_t stream) {
  const float* feat  = (const float*)d_in[0];
  const float* boxes = (const float*)d_in[1];
  const float* W1    = (const float*)d_in[2];
  const float* b1    = (const float*)d_in[3];
  const float* W2    = (const float*)d_in[4];
  const float* b2    = (const float*)d_in[5];
  const float* Wc    = (const float*)d_in[6];
  const float* bc    = (const float*)d_in[7];
  const float* Wr    = (const float*)d_in[8];
  const float* br    = (const float*)d_in[9];
  float* out = (float*)d_out;

  // workspace layout (bytes)
  char* ws = (char*)d_ws;
  unsigned short* pooled = (unsigned short*)(ws);                  // 256*25088*2   = 12,845,056
  float*          part   = (float*)(ws + 12845056);                // 8*256*4096*4  = 33,554,432
  unsigned short* x1     = (unsigned short*)(ws + 46399488);       // 256*4096*2    =  2,097,152
  unsigned short* x2     = (unsigned short*)(ws + 48496640);       // 256*4096*2    =  2,097,152
  float*          hpart  = (float*)(ws + 50593792);                // 16*256*128*4  =  2,097,152
                                                                   // total ~52.7 MB
  // featT [H*W, C] = 5,120,000 B aliases the `part` region: featT is dead
  // before FC1 writes part (same stream, sequential dispatches).
  float*          featT  = part;

  // 1) transpose features for coalesced pooling, then ROI pool -> bf16 [256, 25088]
  transpose_feat<<<HFEAT * WFEAT, 512, 0, stream>>>(feat, featT);
  roi_pool_kernel<<<NROIS, 512, 0, stream>>>(featT, boxes, pooled);

  // 2) FC1: [256,25088] x [4096,25088]^T, splitK=8 (kps=3136), grid 8z x 128bn
  gemm_bt_splitk<8, false><<<dim3(1024), 256, 0, stream>>>(pooled, W1, W1, part,
      H1, D1, 3136, H1);
  reduce_bias_relu<<<1024, 256, 0, stream>>>(part, b1, x1, NROIS * H1, H1 - 1, 8);

  // 3) FC2: [256,4096] x [4096,4096]^T, splitK=8 (kps=512)
  gemm_bt_splitk<8, false><<<dim3(1024), 256, 0, stream>>>(x1, W2, W2, part,
      H1, H1, 512, H1);
  reduce_bias_relu<<<1024, 256, 0, stream>>>(part, b2, x2, NROIS * H1, H1 - 1, 8);

  // 4) heads: [256,4096] x [105,4096]^T (N padded to 128), splitK=16 (kps=256)
  //    Wc/Wr fused via per-row pointer select (no concat copy needed).
  gemm_bt_splitk<16, true><<<dim3(64), 256, 0, stream>>>(x2, Wc, Wr, hpart,
      128, H1, 256, NHEAD);
  heads_reduce<<<NROIS, 128, 0, stream>>>(hpart, bc, br, out, 16);
}

// Round 4
// 797.031 us; speedup vs baseline: 1.1222x; 1.1222x over previous
//
#include <hip/hip_runtime.h>

// ---------------- problem constants ----------------
#define C_CH   512
#define HFEAT  50
#define WFEAT  50
#define NROIS  256
#define D1     25088   // C_CH * 49
#define H1     4096
#define NHEAD  105     // 21 + 84

typedef __attribute__((ext_vector_type(8))) short short8;
typedef __attribute__((ext_vector_type(4))) float f32x4;

__device__ __forceinline__ unsigned short f2bf(float f) {
  unsigned int u = __float_as_uint(f);
  unsigned int r = (u + 0x7fffu + ((u >> 16) & 1u)) >> 16;
  return (unsigned short)r;
}

// ---------------- feature transpose: [C,H,W] -> [H*W, C] ----------------
__global__ __launch_bounds__(512)
void transpose_feat(const float* __restrict__ feat, float* __restrict__ featT) {
  const int yx = blockIdx.x;        // 0 .. 2499
  const int c  = threadIdx.x;       // 0 .. 511
  featT[(size_t)yx * C_CH + c] = feat[(size_t)c * (HFEAT * WFEAT) + yx];
}

// ---------------- ROI max-pool (adaptive 7x7), fp32 -> bf16 ----------------
__global__ __launch_bounds__(512)
void roi_pool_kernel(const float* __restrict__ featT, const float* __restrict__ boxes,
                     unsigned short* __restrict__ pooled) {
  const int roi = blockIdx.x;
  const int bx1 = (int)(boxes[roi * 4 + 0] * 0.0625f);
  const int by1 = (int)(boxes[roi * 4 + 1] * 0.0625f);
  const int bx2 = (int)(boxes[roi * 4 + 2] * 0.0625f);
  const int by2 = (int)(boxes[roi * 4 + 3] * 0.0625f);

  const int rlo = min(max(by1, 0), HFEAT - 1);
  const int rhi = min(by2, HFEAT - 1);
  const int rn  = max(rhi - rlo + 1, 1);
  const int clo = min(max(bx1, 0), WFEAT - 1);
  const int chi = min(bx2, WFEAT - 1);
  const int cn  = max(chi - clo + 1, 1);

  const int c = threadIdx.x;                      // one channel per thread
  unsigned short* op = pooled + (size_t)roi * D1 + c * 49;

  for (int i = 0; i < 7; ++i) {
    const int r0 = rlo + (i * rn) / 7;
    const int r1 = rlo + ((i + 1) * rn + 6) / 7;
    for (int j = 0; j < 7; ++j) {
      const int c0 = clo + (j * cn) / 7;
      const int c1 = clo + ((j + 1) * cn + 6) / 7;
      float m = -3.402823466e+38f;
      for (int y = r0; y < r1; ++y)
        for (int x = c0; x < c1; ++x)
          m = fmaxf(m, featT[(size_t)(y * WFEAT + x) * C_CH + c]);
      op[i * 7 + j] = f2bf(m);
    }
  }
}

// ---------------- split-K MFMA GEMM: A[256,K] bf16  x  B[N,K] fp32 -> partials fp32 ----------------
// BM=256 (whole M), BN=64, BK=32, 256 threads = 4 waves (2m x 2n of 128x32 each).
// Each (z,bn) block owns a UNIQUE 64-row B slice -> B streamed from HBM exactly
// once. A's z-slice (<=1.6MB bf16) is L2-resident per XCD via z = bid % NZ.
//
// LDS XOR-swizzle (fix for 8-way ds_read_b128 bank conflicts, 14.4M conflict-cyc
// measured on the linear layout): 16B-slot s of row r holds data of slot
// s ^ ((r>>1)&3). Applied BOTH-sides (rule #21):
//   - As: global_load_lds keeps a LINEAR LDS dest; the global SOURCE column is
//     pre-swizzled per-lane: scol = ((lane&3) ^ ((lane>>3)&3)) * 8.
//   - Bs: reg-staged, ds_write address swizzled directly.
//   - fragment reads XOR kq with (lr>>1)&3.
// Resulting read slot-index (lr&1)*4 + (kq^((lr>>1)&3)) covers all 8 16B-slots
// over 8 rows -> 2-way max (free).
template <int NZ, bool TWO_B>
__global__ __launch_bounds__(256)
void gemm_bt_splitk(const unsigned short* __restrict__ A,  // [256,K] bf16 bits
                    const float* __restrict__ B,           // [*,K] fp32
                    const float* __restrict__ B2,          // [*,K] fp32 (heads only)
                    float* __restrict__ part,              // [NZ, 256, Nt]
                    const int Nt, const int K,
                    const int kps, const int n_valid) {
  __shared__ __align__(16) unsigned short As[256 * 32];   // 16 KB
  __shared__ __align__(16) unsigned short Bs[64 * 32];    //  4 KB

  const int bid = (int)blockIdx.x;
  const int z   = bid % NZ;                 // -> XCD pin per dispatch heuristic
  const int bn  = (bid / NZ) * 64;
  const int k0  = z * kps;
  const int k1  = k0 + kps;

  const int tid  = threadIdx.x;
  const int wave = tid >> 6;
  const int lane = tid & 63;
  const int lr   = lane & 15;   // fragment row (m or n)
  const int kq   = lane >> 4;   // k-quad: k = kq*8 .. +7
  const int wm   = (wave & 1) * 128;
  const int wn   = (wave >> 1) * 32;
  const int kqs  = kq ^ ((lr >> 1) & 3);    // swizzled k-slot for fragment reads

  // A staging: pre-swizzled global source column (LDS dest stays linear)
  const int scol = ((lane & 3) ^ ((lane >> 3) & 3)) * 8;

  // B staging: 4 threads per row, 8 floats each; swizzled LDS slot
  const int  brow   = tid >> 2;          // 0..63
  const int  bslot  = (tid & 3) ^ ((tid >> 3) & 3);
  const int  nrow   = bn + brow;
  const bool bvalid = nrow < n_valid;
  const float* bsrc;
  if (TWO_B) {
    if (nrow < 21)       bsrc = B  + (size_t)nrow * K + (tid & 3) * 8;
    else if (bvalid)     bsrc = B2 + (size_t)(nrow - 21) * K + (tid & 3) * 8;
    else                 bsrc = B  + (tid & 3) * 8;   // never dereferenced
  } else {
    bsrc = B + (size_t)nrow * K + (tid & 3) * 8;
  }

  f32x4 acc[8][2];
#pragma unroll
  for (int im = 0; im < 8; ++im)
#pragma unroll
    for (int in = 0; in < 2; ++in)
      acc[im][in] = (f32x4){0.f, 0.f, 0.f, 0.f};

  for (int kk = k0; kk < k1; kk += 32) {
    __syncthreads();
    // ---- stage A tile (256x32 bf16 = 16KB) via global_load_lds, 4 insts/wave ----
#pragma unroll
    for (int i = 0; i < 4; ++i) {
      const int chunk = wave * 4 + i;            // 0..15, wave-uniform
      const int row   = chunk * 16 + (lane >> 2);
      const unsigned short* g = A + (size_t)row * K + kk + scol;
      __builtin_amdgcn_global_load_lds(
          (const __attribute__((address_space(1))) void*)g,
          (__attribute__((address_space(3))) void*)(As + chunk * 512),
          16, 0, 0);
    }
    // ---- stage B tile (64x32): fp32 load -> bf16 convert -> LDS (swizzled) ----
    {
      float v[8];
      if (bvalid) {
        const float4* g = (const float4*)(bsrc + kk);
        const float4 t0 = g[0];
        const float4 t1 = g[1];
        v[0] = t0.x; v[1] = t0.y; v[2] = t0.z; v[3] = t0.w;
        v[4] = t1.x; v[5] = t1.y; v[6] = t1.z; v[7] = t1.w;
      } else {
#pragma unroll
        for (int q = 0; q < 8; ++q) v[q] = 0.f;
      }
      union { unsigned short h[8]; ulonglong2 u; } tmp;
#pragma unroll
      for (int q = 0; q < 8; ++q) tmp.h[q] = f2bf(v[q]);
      *(ulonglong2*)(Bs + brow * 32 + bslot * 8) = tmp.u;
    }
    __syncthreads();
    // ---- fragments + 16 MFMAs per wave ----
    short8 af[8], bf[2];
#pragma unroll
    for (int im = 0; im < 8; ++im)
      af[im] = *(const short8*)(As + (wm + im * 16 + lr) * 32 + kqs * 8);
#pragma unroll
    for (int in = 0; in < 2; ++in)
      bf[in] = *(const short8*)(Bs + (wn + in * 16 + lr) * 32 + kqs * 8);
#pragma unroll
    for (int im = 0; im < 8; ++im)
#pragma unroll
      for (int in = 0; in < 2; ++in)
        acc[im][in] = __builtin_amdgcn_mfma_f32_16x16x32_bf16(af[im], bf[in], acc[im][in], 0, 0, 0);
  }

  // ---- write fp32 partials: C/D layout col=lane&15 (n), row=kq*4+r (m) ----
#pragma unroll
  for (int im = 0; im < 8; ++im) {
#pragma unroll
    for (int in = 0; in < 2; ++in) {
      const int m0 = wm + im * 16 + kq * 4;
      const int n  = bn + wn + in * 16 + lr;
      float* p = part + ((size_t)z * NROIS + m0) * Nt + n;
#pragma unroll
      for (int r = 0; r < 4; ++r)
        p[(size_t)r * Nt] = acc[im][in][r];
    }
  }
}

// ---------------- split-K reduce + bias + relu + cast to bf16 ----------------
__global__ __launch_bounds__(256)
void reduce_bias_relu(const float* __restrict__ part, const float* __restrict__ bias,
                      unsigned short* __restrict__ out, const int MN, const int nmask,
                      const int S) {
  const int idx = (blockIdx.x * 256 + threadIdx.x) * 4;
  if (idx >= MN) return;
  float4 v = *(const float4*)(part + idx);
  for (int s = 1; s < S; ++s) {
    const float4 p = *(const float4*)(part + (size_t)s * MN + idx);
    v.x += p.x; v.y += p.y; v.z += p.z; v.w += p.w;
  }
  const float4 b = *(const float4*)(bias + (idx & nmask));
  v.x = fmaxf(v.x + b.x, 0.f);
  v.y = fmaxf(v.y + b.y, 0.f);
  v.z = fmaxf(v.z + b.z, 0.f);
  v.w = fmaxf(v.w + b.w, 0.f);
  unsigned long long o = (unsigned long long)f2bf(v.x)
                       | ((unsigned long long)f2bf(v.y) << 16)
                       | ((unsigned long long)f2bf(v.z) << 32)
                       | ((unsigned long long)f2bf(v.w) << 48);
  *(unsigned long long*)(out + idx) = o;
}

// ---------------- heads: reduce + bias, split into class/regr outputs ----------------
__global__ __launch_bounds__(128)
void heads_reduce(const float* __restrict__ part, const float* __restrict__ bc,
                  const float* __restrict__ br, float* __restrict__ out, const int S) {
  const int m = blockIdx.x;
  const int n = threadIdx.x;
  if (n >= NHEAD) return;
  float v = 0.f;
  for (int s = 0; s < S; ++s) v += part[((size_t)s * NROIS + m) * 128 + n];
  if (n < 21) out[m * 21 + n] = v + bc[n];
  else        out[NROIS * 21 + m * 84 + (n - 21)] = v + br[n - 21];
}

// ---------------- launch ----------------
extern "C" void kernel_launch(void* const* d_in, const int* in_sizes, int n_in,
                              void* d_out, int out_size, void* d_ws, size_t ws_size,
                              hipStream_t stream) {
  const float* feat  = (const float*)d_in[0];
  const float* boxes = (const float*)d_in[1];
  const float* W1    = (const float*)d_in[2];
  const float* b1    = (const float*)d_in[3];
  const float* W2    = (const float*)d_in[4];
  const float* b2    = (const float*)d_in[5];
  const float* Wc    = (const float*)d_in[6];
  const float* bc    = (const float*)d_in[7];
  const float* Wr    = (const float*)d_in[8];
  const float* br    = (const float*)d_in[9];
  float* out = (float*)d_out;

  // workspace layout (bytes)
  char* ws = (char*)d_ws;
  unsigned short* pooled = (unsigned short*)(ws);                  // 256*25088*2   = 12,845,056
  float*          part   = (float*)(ws + 12845056);                // 8*256*4096*4  = 33,554,432
  unsigned short* x1     = (unsigned short*)(ws + 46399488);       // 256*4096*2    =  2,097,152
  unsigned short* x2     = (unsigned short*)(ws + 48496640);       // 256*4096*2    =  2,097,152
  float*          hpart  = (float*)(ws + 50593792);                // 16*256*128*4  =  2,097,152
                                                                   // total ~52.7 MB
  // featT [H*W, C] = 5,120,000 B aliases the `part` region: featT is dead
  // before FC1 writes part (same stream, sequential dispatches).
  float*          featT  = part;

  // 1) transpose features for coalesced pooling, then ROI pool -> bf16 [256, 25088]
  transpose_feat<<<HFEAT * WFEAT, 512, 0, stream>>>(feat, featT);
  roi_pool_kernel<<<NROIS, 512, 0, stream>>>(featT, boxes, pooled);

  // 2) FC1: [256,25088] x [4096,25088]^T, splitK=8 (kps=3136), grid 8z x 64bn
  gemm_bt_splitk<8, false><<<dim3(512), 256, 0, stream>>>(pooled, W1, W1, part,
      H1, D1, 3136, H1);
  reduce_bias_relu<<<1024, 256, 0, stream>>>(part, b1, x1, NROIS * H1, H1 - 1, 8);

  // 3) FC2: [256,4096] x [4096,4096]^T, splitK=8 (kps=512)
  gemm_bt_splitk<8, false><<<dim3(512), 256, 0, stream>>>(x1, W2, W2, part,
      H1, H1, 512, H1);
  reduce_bias_relu<<<1024, 256, 0, stream>>>(part, b2, x2, NROIS * H1, H1 - 1, 8);

  // 4) heads: [256,4096] x [105,4096]^T (N padded to 128), splitK=16 (kps=256)
  //    Wc/Wr fused via per-row pointer select (no concat copy needed).
  gemm_bt_splitk<16, true><<<dim3(32), 256, 0, stream>>>(x2, Wc, Wr, hpart,
      128, H1, 256, NHEAD);
  heads_reduce<<<NROIS, 128, 0, stream>>>(hpart, bc, br, out, 16);
}